// Round 25
// baseline (169.059 us; speedup 1.0000x reference)
//
#include <hip/hip_runtime.h>
#include <math.h>

#define NN 128
#define FF 64
#define KK 50
#define NI 640               // intervals; h = 10/640
#define EPSV 1e-6f

// ws layout (floats):
// dws: [B*N*N]   off 0
// T:   [B*N*N]   off 524288
// A:   [NI][64][3] float4 off 1048576 (ends 1540096)  fwd cubic coeffs
// B:   same layout,        off 1540096 (ends 2031616) bwd cubic coeffs
// WT:  4 x 4096 floats     off 2031616 (ends 2048000) transposed Wt1, W2a, W2b, W2c
// C:   [B*N*3*64] off 2097152   (us sums from k_fwdp, then C in place via k_epi)
// Fr:  [B*N*3]    off 2883584

__device__ __forceinline__ float softplus_fast(float z) {
    float e = __expf(-fabsf(z));
    float l = __logf(1.f + e);
    return fmaxf(z, 0.f) + l;
}

// fused: [0,2048) distances; [2048,2528) fp32 table build (thread per (j,f,l));
//        [2528,2592) weight transposes
__global__ __launch_bounds__(256) void k_dt(
    const float* __restrict__ xs, float* __restrict__ dws,
    const float* __restrict__ W1a, const float* __restrict__ W1b, const float* __restrict__ W1c,
    const float* __restrict__ b1a, const float* __restrict__ b1b, const float* __restrict__ b1c,
    const float* __restrict__ mus, const float* __restrict__ gamma,
    float4* __restrict__ Af, float4* __restrict__ Bf,
    const float* __restrict__ Wt1,
    const float* __restrict__ W2a, const float* __restrict__ W2b, const float* __restrict__ W2c,
    float* __restrict__ WT)
{
    int bid = blockIdx.x;
    if (bid < 2048) {
        int tid = bid * 256 + threadIdx.x;
        int b = tid >> 14;
        int rem = tid & 16383;
        int i = rem >> 7, a = rem & 127;
        const float* xb = xs + b * (NN * 3);
        float dx = xb[i*3+0] - xb[a*3+0];
        float dy = xb[i*3+1] - xb[a*3+1];
        float dz = xb[i*3+2] - xb[a*3+2];
        dws[tid] = sqrtf(dx*dx + dy*dy + dz*dz + EPSV);
        return;
    }
    if (bid < 2528) {
        int idx = (bid - 2048) * 256 + threadIdx.x;   // NI*64*3 = 122880
        if (idx >= NI * 64 * 3) return;
        int l = idx / (NI * 64);
        int r = idx - l * (NI * 64);
        int j = r >> 6, f = r & 63;
        int base4 = j * 192 + f * 3;
        float h = 10.0f / (float)NI;
        float gam = gamma[0];
        const float* W  = (l == 0) ? W1a : (l == 1) ? W1b : W1c;
        const float* bb = (l == 0) ? b1a : (l == 1) ? b1b : b1c;
        float G[2], Gp[2], Gpp[2];
        float g2 = 4.f * gam * gam;
        for (int e = 0; e < 2; ++e) {
            float d = (float)(j + e) * h;
            float z = bb[f], zp = 0.f, zpp = 0.f;
            for (int k = 0; k < KK; ++k) {
                float x = d - mus[k];
                float ee = __expf(-gam * x * x);
                float we = W[k * 64 + f] * ee;
                z   += we;
                zp   = fmaf(we, -2.f * gam * x, zp);
                zpp  = fmaf(we, fmaf(g2 * x, x, -2.f * gam), zpp);
            }
            float sg = 1.f / (1.f + __expf(-z));
            G[e]   = softplus_fast(z);
            Gp[e]  = sg * zp;
            Gpp[e] = sg * (1.f - sg) * zp * zp + sg * zpp;
        }
        {
            float p0 = G[0], m0 = h * Gp[0], p1 = G[1], m1 = h * Gp[1];
            Af[base4 + l] = make_float4(
                p0, m0,
                3.f * (p1 - p0) - 2.f * m0 - m1,
                2.f * (p0 - p1) + m0 + m1);
        }
        {
            float q0 = Gp[0], n0 = h * Gpp[0], q1 = Gp[1], n1 = h * Gpp[1];
            Bf[base4 + l] = make_float4(
                q0, n0,
                3.f * (q1 - q0) - 2.f * n0 - n1,
                2.f * (q0 - q1) + n0 + n1);
        }
        return;
    }
    int idx = (bid - 2528) * 256 + threadIdx.x;   // 4*4096 = 16384
    if (idx < 16384) {
        int which = idx >> 12;
        int r = idx & 4095;
        int m = r >> 6, f = r & 63;
        const float* src = (which == 0) ? Wt1 : (which == 1) ? W2a : (which == 2) ? W2b : W2c;
        WT[idx] = src[f * 64 + m];    // WT[which][m*64+f] = src[f][m]
    }
}

// ------- forward pair pass: 2 atoms x 2 pair-halves, batch-8 staged loads -------
__global__ __launch_bounds__(256, 1) void k_fwdp(
    const float* __restrict__ dws, const float4* __restrict__ A4,
    float* __restrict__ usout)
{
    __shared__ float dsh[2][128];
    __shared__ float ush[2][2][3][64];   // [ai][half][layer][f]
    int tid = threadIdx.x;
    int wave = tid >> 6, lane = tid & 63;
    int ai = wave >> 1, half = wave & 1;
    int atom = blockIdx.x * 2 + ai;
    int i = atom & 127;
    const float* drow = dws + (atom << 7);
    dsh[ai][half * 64 + lane] = drow[half * 64 + lane];
    __syncthreads();

    const float invh = (float)NI / 10.0f;
    const float4* Afp = A4 + 3 * lane;
    double us0 = 0.0, us1 = 0.0, us2 = 0.0;
    int obase = 1 + (half << 6);       // 1 or 65
    int lim = half ? 63 : 64;          // offsets handled by this wave

    #pragma unroll 1
    for (int g = 0; g < 2; ++g) {
        float ut0 = 0.f, ut1 = 0.f, ut2 = 0.f;
        int gb = g << 5;
        int nb = lim - gb; if (nb > 32) nb = 32;
        int nb8 = nb & ~7;
        #pragma unroll 1
        for (int bb = 0; bb < nb8; bb += 8) {
            float tt[8];
            float4 u0[8], u1[8], u2[8];
            #pragma unroll
            for (int p = 0; p < 8; ++p) {
                float d = dsh[ai][(i + obase + gb + bb + p) & 127];
                float fd = fminf(d * invh, (float)NI - 0.001f);
                float jf = floorf(fd);
                tt[p] = fd - jf;
                int j4 = (int)jf * 192;
                u0[p] = Afp[j4];
                u1[p] = Afp[j4 + 1];
                u2[p] = Afp[j4 + 2];
            }
            #pragma unroll
            for (int p = 0; p < 8; ++p) {
                float t1 = tt[p];
                ut0 += fmaf(t1, fmaf(t1, fmaf(t1, u0[p].w, u0[p].z), u0[p].y), u0[p].x);
                ut1 += fmaf(t1, fmaf(t1, fmaf(t1, u1[p].w, u1[p].z), u1[p].y), u1[p].x);
                ut2 += fmaf(t1, fmaf(t1, fmaf(t1, u2[p].w, u2[p].z), u2[p].y), u2[p].x);
            }
        }
        for (int p = nb8; p < nb; ++p) {
            float d = dsh[ai][(i + obase + gb + p) & 127];
            float fd = fminf(d * invh, (float)NI - 0.001f);
            float jf = floorf(fd);
            float t1 = fd - jf;
            int j4 = (int)jf * 192;
            float4 c0 = Afp[j4];
            float4 c1 = Afp[j4 + 1];
            float4 c2 = Afp[j4 + 2];
            ut0 += fmaf(t1, fmaf(t1, fmaf(t1, c0.w, c0.z), c0.y), c0.x);
            ut1 += fmaf(t1, fmaf(t1, fmaf(t1, c1.w, c1.z), c1.y), c1.x);
            ut2 += fmaf(t1, fmaf(t1, fmaf(t1, c2.w, c2.z), c2.y), c2.x);
        }
        us0 += (double)ut0; us1 += (double)ut1; us2 += (double)ut2;
    }

    ush[ai][half][0][lane] = (float)us0;
    ush[ai][half][1][lane] = (float)us1;
    ush[ai][half][2][lane] = (float)us2;
    __syncthreads();
    if (half == 0) {
        float* uo = usout + atom * 192;
        uo[lane]       = ush[ai][0][0][lane] + ush[ai][1][0][lane];
        uo[64 + lane]  = ush[ai][0][1][lane] + ush[ai][1][1][lane];
        uo[128 + lane] = ush[ai][0][2][lane] + ush[ai][1][2][lane];
    }
}

// ------- per-atom epilogue: all matvecs coalesced via transposed weights -------
__global__ __launch_bounds__(256) void k_epi(
    float* __restrict__ CU,
    const float* __restrict__ W2a, const float* __restrict__ W2b, const float* __restrict__ W2c,
    const float* __restrict__ b2a, const float* __restrict__ b2b, const float* __restrict__ b2c,
    const float* __restrict__ Wenc, const float* __restrict__ benc,
    const float* __restrict__ Wt1, const float* __restrict__ bt1, const float* __restrict__ Wt2,
    const float* __restrict__ WT)
{
    __shared__ double epid[4][FF];
    __shared__ float  epif[4][FF];
    const float* Wt1T = WT;           // Wt1T[m*64+f] = Wt1[f*64+m]
    const float* W2aT = WT + 4096;
    const float* W2bT = WT + 8192;
    const float* W2cT = WT + 12288;
    int tid = threadIdx.x;
    int wave = tid >> 6, lane = tid & 63, f = lane;
    int atom = blockIdx.x * 4 + wave;

    double us0 = (double)CU[atom * 192 + lane];
    double us1 = (double)CU[atom * 192 + 64 + lane];
    double us2 = (double)CU[atom * 192 + 128 + lane];

    double wf0, wf1, wf2;
    {
        epid[wave][lane] = us0;
        double acc = 0.0;
        for (int m = 0; m < 64; ++m) acc += epid[wave][m] * (double)W2a[m*64 + f];
        wf0 = 1.0 + acc + 127.0 * (double)b2a[f];

        epid[wave][lane] = us1;
        double acc1 = 0.0;
        for (int m = 0; m < 64; ++m) acc1 += epid[wave][m] * (double)W2b[m*64 + f];
        wf1 = 1.0 + acc1 + 127.0 * (double)b2b[f];

        epid[wave][lane] = us2;
        double acc2 = 0.0;
        for (int m = 0; m < 64; ++m) acc2 += epid[wave][m] * (double)W2c[m*64 + f];
        wf2 = 1.0 + acc2 + 127.0 * (double)b2c[f];
    }
    double h0 = (double)Wenc[f] + (double)benc[f];
    double h  = h0 * wf0 * wf1 * wf2;
    epid[wave][lane] = h;
    double pre = (double)bt1[lane];
    for (int m = 0; m < 64; ++m) pre += epid[wave][m] * (double)Wt1[m*64 + lane];
    double tv = tanh(pre);
    float gv = (float)((1.0 - tv * tv) * (double)Wt2[lane]);

    float p1 = (float)(h0 * wf1 * wf2);
    float p2 = (float)(h0 * wf0 * wf2);
    float p3 = (float)(h0 * wf0 * wf1);

    epif[wave][lane] = gv;
    float dv = 0.f;
    for (int m = 0; m < 64; ++m) dv = fmaf(epif[wave][m], Wt1T[m*64 + lane], dv);

    float* co = CU + atom * 192;
    epif[wave][lane] = dv * p1;
    float c0 = 0.f;
    for (int m = 0; m < 64; ++m) c0 = fmaf(epif[wave][m], W2aT[m*64 + lane], c0);
    co[lane] = c0;

    epif[wave][lane] = dv * p2;
    float c1 = 0.f;
    for (int m = 0; m < 64; ++m) c1 = fmaf(epif[wave][m], W2bT[m*64 + lane], c1);
    co[64 + lane] = c1;

    epif[wave][lane] = dv * p3;
    float c2 = 0.f;
    for (int m = 0; m < 64; ++m) c2 = fmaf(epif[wave][m], W2cT[m*64 + lane], c2);
    co[128 + lane] = c2;
}

// ------- backward: 2 atoms x 2 offset-halves, batch-8 staged loads -------
__global__ __launch_bounds__(256, 1) void k_bwd(
    const float* __restrict__ dws, const float4* __restrict__ B4,
    const float* __restrict__ C, float* __restrict__ T)
{
    __shared__ float dsh[2][128];
    int tid = threadIdx.x;
    int wave = tid >> 6, lane = tid & 63;
    int ai = wave >> 1, half = wave & 1;
    int atom = blockIdx.x * 2 + ai;
    int b = atom >> 7, i = atom & 127;
    const float* drow = dws + (atom << 7);
    dsh[ai][half * 64 + lane] = drow[half * 64 + lane];
    __syncthreads();

    const float* ci = C + atom * 192;
    float ci0 = ci[lane], ci1 = ci[64 + lane], ci2 = ci[128 + lane];
    float* Tb = T + ((size_t)b << 14);
    const float invh = (float)NI / 10.0f;
    const float4* Bfp = B4 + 3 * lane;
    float vm = 0.f;

    #pragma unroll 1
    for (int g = 0; g < 4; ++g) {
        int offb = 1 + (half << 5) + (g << 3);
        float tt[8], cA[8], cB[8], cC[8];
        float4 u0[8], u1[8], u2[8];
        #pragma unroll
        for (int p = 0; p < 8; ++p) {
            int aa = (i + offb + p) & 127;
            float d = dsh[ai][aa];
            float fd = fminf(d * invh, (float)NI - 0.001f);
            float jf = floorf(fd);
            tt[p] = fd - jf;
            int j4 = (int)jf * 192;
            u0[p] = Bfp[j4];
            u1[p] = Bfp[j4 + 1];
            u2[p] = Bfp[j4 + 2];
            const float* ca = C + (((b << 7) + aa) * 192);
            cA[p] = ca[lane]; cB[p] = ca[64 + lane]; cC[p] = ca[128 + lane];
        }
        #pragma unroll
        for (int p = 0; p < 8; ++p) {
            float t1 = tt[p];
            float g0 = fmaf(t1, fmaf(t1, fmaf(t1, u0[p].w, u0[p].z), u0[p].y), u0[p].x);
            float g1 = fmaf(t1, fmaf(t1, fmaf(t1, u1[p].w, u1[p].z), u1[p].y), u1[p].x);
            float g2 = fmaf(t1, fmaf(t1, fmaf(t1, u2[p].w, u2[p].z), u2[p].y), u2[p].x);
            float red = (ci0 + cA[p]) * g0 + (ci1 + cB[p]) * g1 + (ci2 + cC[p]) * g2;
            #pragma unroll
            for (int o = 1; o < 64; o <<= 1) red += __shfl_xor(red, o);
            if (lane == (g << 3) + p) vm = red;
        }
    }
    int off = 1 + (half << 5) + lane;     // lanes 0..31 hold this wave's offsets
    if (lane < 32 && (off < 64 || i < 64)) {
        int a = (i + off) & 127;
        Tb[(i << 7) + a] = vm;
        Tb[(a << 7) + i] = vm;
    }
}

__global__ __launch_bounds__(256) void k_force(
    const float* __restrict__ xs, const float* __restrict__ dws,
    const float* __restrict__ T, float* __restrict__ Fr)
{
    int tid = threadIdx.x;
    int wave = tid >> 6, lane = tid & 63;
    int atom = blockIdx.x * 4 + wave;
    int i = atom & 127;
    int b = atom >> 7;
    const float* xb = xs + b * (NN * 3);
    float xi0 = xb[i*3], xi1 = xb[i*3+1], xi2 = xb[i*3+2];
    const float* drow = dws + (atom << 7);
    const float* trow = T + (atom << 7);
    float fx = 0.f, fy = 0.f, fz = 0.f;
    for (int it = lane; it < 127; it += 64) {
        int aa = (i + 1 + it) & 127;
        float coef = trow[aa] / drow[aa];
        fx += coef * (xi0 - xb[aa*3]);
        fy += coef * (xi1 - xb[aa*3+1]);
        fz += coef * (xi2 - xb[aa*3+2]);
    }
    #pragma unroll
    for (int off = 1; off < 64; off <<= 1) {
        fx += __shfl_xor(fx, off);
        fy += __shfl_xor(fy, off);
        fz += __shfl_xor(fz, off);
    }
    if (lane == 0) {
        Fr[atom*3]   = fx;
        Fr[atom*3+1] = fy;
        Fr[atom*3+2] = fz;
    }
}

__global__ __launch_bounds__(128) void k_out(const float* __restrict__ Fr, float* __restrict__ out)
{
    __shared__ float rs[3][128];
    int b = blockIdx.x, n = threadIdx.x;
    float g0 = Fr[(b*128+n)*3], g1 = Fr[(b*128+n)*3+1], g2 = Fr[(b*128+n)*3+2];
    rs[0][n] = g0; rs[1][n] = g1; rs[2][n] = g2;
    __syncthreads();
    for (int s = 64; s > 0; s >>= 1) {
        if (n < s) {
            rs[0][n] += rs[0][n+s];
            rs[1][n] += rs[1][n+s];
            rs[2][n] += rs[2][n+s];
        }
        __syncthreads();
    }
    float m0 = rs[0][0] * (1.f/128.f);
    float m1 = rs[1][0] * (1.f/128.f);
    float m2 = rs[2][0] * (1.f/128.f);
    out[b*384 + n*3 + 0] = m0 - g0;
    out[b*384 + n*3 + 1] = m1 - g1;
    out[b*384 + n*3 + 2] = m2 - g2;
}

extern "C" void kernel_launch(void* const* d_in, const int* in_sizes, int n_in,
                              void* d_out, int out_size, void* d_ws, size_t ws_size,
                              hipStream_t stream)
{
    const float* xs   = (const float*)d_in[1];
    const float* mus  = (const float*)d_in[2];
    const float* gam  = (const float*)d_in[3];
    const float* Wenc = (const float*)d_in[4];
    const float* benc = (const float*)d_in[5];
    const float* W1a  = (const float*)d_in[6];
    const float* b1a  = (const float*)d_in[7];
    const float* W2a  = (const float*)d_in[8];
    const float* b2a  = (const float*)d_in[9];
    const float* W1b  = (const float*)d_in[10];
    const float* b1b  = (const float*)d_in[11];
    const float* W2b  = (const float*)d_in[12];
    const float* b2b  = (const float*)d_in[13];
    const float* W1c  = (const float*)d_in[14];
    const float* b1c  = (const float*)d_in[15];
    const float* W2c  = (const float*)d_in[16];
    const float* b2c  = (const float*)d_in[17];
    const float* Wt1  = (const float*)d_in[18];
    const float* bt1  = (const float*)d_in[19];
    const float* Wt2  = (const float*)d_in[20];

    float* ws  = (float*)d_ws;
    float* dws = ws;
    float* T   = ws + 524288;
    float4* A4 = (float4*)(ws + 1048576);
    float4* B4 = (float4*)(ws + 1540096);
    float* WT  = ws + 2031616;
    float* C   = ws + 2097152;
    float* Fr  = ws + 2883584;
    float* out = (float*)d_out;

    k_dt   <<<2592, 256, 0, stream>>>(xs, dws, W1a, W1b, W1c, b1a, b1b, b1c,
                                      mus, gam, A4, B4, Wt1, W2a, W2b, W2c, WT);
    k_fwdp <<<2048, 256, 0, stream>>>(dws, A4, C);
    k_epi  <<<1024, 256, 0, stream>>>(C, W2a, W2b, W2c, b2a, b2b, b2c,
                                      Wenc, benc, Wt1, bt1, Wt2, WT);
    k_bwd  <<<2048, 256, 0, stream>>>(dws, B4, C, T);
    k_force<<<1024, 256, 0, stream>>>(xs, dws, T, Fr);
    k_out  <<<32, 128, 0, stream>>>(Fr, out);
}

// Round 26
// 133.212 us; speedup vs baseline: 1.2691x; 1.2691x over previous
//
#include <hip/hip_runtime.h>
#include <math.h>

#define NN 128
#define FF 64
#define KK 50
#define NI 640               // intervals; h = 10/640
#define EPSV 1e-6f

// ws layout (floats):
// dws: [B*N*N]   off 0
// T:   [B*N*N]   off 524288
// A:   [NI][3][64] float4 off 1048576 (ends 1540096)  fwd cubic coeffs (lane-contiguous)
// B:   same layout,        off 1540096 (ends 2031616) bwd cubic coeffs
// WT:  4 x 4096 floats     off 2031616 (ends 2048000) transposed Wt1, W2a, W2b, W2c
// C:   [B*N*3*64] off 2097152   (us sums from k_fwdp, then C in place via k_epi)
// Fr:  [B*N*3]    off 2883584

__device__ __forceinline__ float softplus_fast(float z) {
    float e = __expf(-fabsf(z));
    float l = __logf(1.f + e);
    return fmaxf(z, 0.f) + l;
}

// fused: [0,2048) distances; [2048,2528) fp32 table build (thread per (j,f,l));
//        [2528,2592) weight transposes
__global__ __launch_bounds__(256) void k_dt(
    const float* __restrict__ xs, float* __restrict__ dws,
    const float* __restrict__ W1a, const float* __restrict__ W1b, const float* __restrict__ W1c,
    const float* __restrict__ b1a, const float* __restrict__ b1b, const float* __restrict__ b1c,
    const float* __restrict__ mus, const float* __restrict__ gamma,
    float4* __restrict__ Af, float4* __restrict__ Bf,
    const float* __restrict__ Wt1,
    const float* __restrict__ W2a, const float* __restrict__ W2b, const float* __restrict__ W2c,
    float* __restrict__ WT)
{
    int bid = blockIdx.x;
    if (bid < 2048) {
        int tid = bid * 256 + threadIdx.x;
        int b = tid >> 14;
        int rem = tid & 16383;
        int i = rem >> 7, a = rem & 127;
        const float* xb = xs + b * (NN * 3);
        float dx = xb[i*3+0] - xb[a*3+0];
        float dy = xb[i*3+1] - xb[a*3+1];
        float dz = xb[i*3+2] - xb[a*3+2];
        dws[tid] = sqrtf(dx*dx + dy*dy + dz*dz + EPSV);
        return;
    }
    if (bid < 2528) {
        int idx = (bid - 2048) * 256 + threadIdx.x;   // NI*64*3 = 122880
        if (idx >= NI * 64 * 3) return;
        int l = idx / (NI * 64);
        int r = idx - l * (NI * 64);
        int j = r >> 6, f = r & 63;
        int base4 = j * 192 + l * 64 + f;             // [j][l][f] float4 layout
        float h = 10.0f / (float)NI;
        float gam = gamma[0];
        const float* W  = (l == 0) ? W1a : (l == 1) ? W1b : W1c;
        const float* bb = (l == 0) ? b1a : (l == 1) ? b1b : b1c;
        float G[2], Gp[2], Gpp[2];
        float g2 = 4.f * gam * gam;
        for (int e = 0; e < 2; ++e) {
            float d = (float)(j + e) * h;
            float z = bb[f], zp = 0.f, zpp = 0.f;
            for (int k = 0; k < KK; ++k) {
                float x = d - mus[k];
                float ee = __expf(-gam * x * x);
                float we = W[k * 64 + f] * ee;
                z   += we;
                zp   = fmaf(we, -2.f * gam * x, zp);
                zpp  = fmaf(we, fmaf(g2 * x, x, -2.f * gam), zpp);
            }
            float sg = 1.f / (1.f + __expf(-z));
            G[e]   = softplus_fast(z);
            Gp[e]  = sg * zp;
            Gpp[e] = sg * (1.f - sg) * zp * zp + sg * zpp;
        }
        {
            float p0 = G[0], m0 = h * Gp[0], p1 = G[1], m1 = h * Gp[1];
            Af[base4] = make_float4(
                p0, m0,
                3.f * (p1 - p0) - 2.f * m0 - m1,
                2.f * (p0 - p1) + m0 + m1);
        }
        {
            float q0 = Gp[0], n0 = h * Gpp[0], q1 = Gp[1], n1 = h * Gpp[1];
            Bf[base4] = make_float4(
                q0, n0,
                3.f * (q1 - q0) - 2.f * n0 - n1,
                2.f * (q0 - q1) + n0 + n1);
        }
        return;
    }
    int idx = (bid - 2528) * 256 + threadIdx.x;   // 4*4096 = 16384
    if (idx < 16384) {
        int which = idx >> 12;
        int r = idx & 4095;
        int m = r >> 6, f = r & 63;
        const float* src = (which == 0) ? Wt1 : (which == 1) ? W2a : (which == 2) ? W2b : W2c;
        WT[idx] = src[f * 64 + m];    // WT[which][m*64+f] = src[f][m]
    }
}

// ------- forward pair pass ONLY: low-VGPR, writes us sums (float) to usout -------
__global__ __launch_bounds__(256) void k_fwdp(
    const float* __restrict__ dws, const float4* __restrict__ A4,
    float* __restrict__ usout)
{
    __shared__ float dsh[4][128];
    int tid = threadIdx.x;
    int wave = tid >> 6, lane = tid & 63;
    int atom = blockIdx.x * 4 + wave;
    int i = atom & 127;
    const float* drow = dws + (atom << 7);
    dsh[wave][lane]      = drow[lane];
    dsh[wave][64 + lane] = drow[64 + lane];
    const float invh = (float)NI / 10.0f;
    const float4* Afp = A4 + lane;
    double us0 = 0.0, us1 = 0.0, us2 = 0.0;

    #pragma unroll 1
    for (int g = 0; g < 4; ++g) {
        float ut0 = 0.f, ut1 = 0.f, ut2 = 0.f;
        int base = g << 5;
        int nb = (g == 3) ? 28 : 32;
        #pragma unroll 1
        for (int bb = 0; bb < nb; bb += 4) {
            float tt[4];
            float4 u0[4], u1[4], u2[4];
            #pragma unroll
            for (int p = 0; p < 4; ++p) {
                float d = dsh[wave][(i + 1 + base + bb + p) & 127];
                float fd = fminf(d * invh, (float)NI - 0.001f);
                float jf = floorf(fd);
                tt[p] = fd - jf;
                int j4 = (int)jf * 192;
                u0[p] = Afp[j4];
                u1[p] = Afp[j4 + 64];
                u2[p] = Afp[j4 + 128];
            }
            #pragma unroll
            for (int p = 0; p < 4; ++p) {
                float t1 = tt[p];
                ut0 += fmaf(t1, fmaf(t1, fmaf(t1, u0[p].w, u0[p].z), u0[p].y), u0[p].x);
                ut1 += fmaf(t1, fmaf(t1, fmaf(t1, u1[p].w, u1[p].z), u1[p].y), u1[p].x);
                ut2 += fmaf(t1, fmaf(t1, fmaf(t1, u2[p].w, u2[p].z), u2[p].y), u2[p].x);
            }
        }
        if (g == 3) {
            #pragma unroll
            for (int p = 124; p < 127; ++p) {
                float d = dsh[wave][(i + 1 + p) & 127];
                float fd = fminf(d * invh, (float)NI - 0.001f);
                float jf = floorf(fd);
                float t1 = fd - jf;
                int j4 = (int)jf * 192;
                float4 c0 = Afp[j4];
                float4 c1 = Afp[j4 + 64];
                float4 c2 = Afp[j4 + 128];
                ut0 += fmaf(t1, fmaf(t1, fmaf(t1, c0.w, c0.z), c0.y), c0.x);
                ut1 += fmaf(t1, fmaf(t1, fmaf(t1, c1.w, c1.z), c1.y), c1.x);
                ut2 += fmaf(t1, fmaf(t1, fmaf(t1, c2.w, c2.z), c2.y), c2.x);
            }
        }
        us0 += (double)ut0; us1 += (double)ut1; us2 += (double)ut2;
    }

    float* uo = usout + atom * 192;
    uo[lane]       = (float)us0;
    uo[64 + lane]  = (float)us1;
    uo[128 + lane] = (float)us2;
}

// ------- per-atom epilogue: all matvecs coalesced via transposed weights -------
__global__ __launch_bounds__(256) void k_epi(
    float* __restrict__ CU,
    const float* __restrict__ W2a, const float* __restrict__ W2b, const float* __restrict__ W2c,
    const float* __restrict__ b2a, const float* __restrict__ b2b, const float* __restrict__ b2c,
    const float* __restrict__ Wenc, const float* __restrict__ benc,
    const float* __restrict__ Wt1, const float* __restrict__ bt1, const float* __restrict__ Wt2,
    const float* __restrict__ WT)
{
    __shared__ double epid[4][FF];
    __shared__ float  epif[4][FF];
    const float* Wt1T = WT;           // Wt1T[m*64+f] = Wt1[f*64+m]
    const float* W2aT = WT + 4096;
    const float* W2bT = WT + 8192;
    const float* W2cT = WT + 12288;
    int tid = threadIdx.x;
    int wave = tid >> 6, lane = tid & 63, f = lane;
    int atom = blockIdx.x * 4 + wave;

    double us0 = (double)CU[atom * 192 + lane];
    double us1 = (double)CU[atom * 192 + 64 + lane];
    double us2 = (double)CU[atom * 192 + 128 + lane];

    double wf0, wf1, wf2;
    {
        epid[wave][lane] = us0;
        double acc = 0.0;
        for (int m = 0; m < 64; ++m) acc += epid[wave][m] * (double)W2a[m*64 + f];
        wf0 = 1.0 + acc + 127.0 * (double)b2a[f];

        epid[wave][lane] = us1;
        double acc1 = 0.0;
        for (int m = 0; m < 64; ++m) acc1 += epid[wave][m] * (double)W2b[m*64 + f];
        wf1 = 1.0 + acc1 + 127.0 * (double)b2b[f];

        epid[wave][lane] = us2;
        double acc2 = 0.0;
        for (int m = 0; m < 64; ++m) acc2 += epid[wave][m] * (double)W2c[m*64 + f];
        wf2 = 1.0 + acc2 + 127.0 * (double)b2c[f];
    }
    double h0 = (double)Wenc[f] + (double)benc[f];
    double h  = h0 * wf0 * wf1 * wf2;
    epid[wave][lane] = h;
    double pre = (double)bt1[lane];
    for (int m = 0; m < 64; ++m) pre += epid[wave][m] * (double)Wt1[m*64 + lane];
    double tv = tanh(pre);
    float gv = (float)((1.0 - tv * tv) * (double)Wt2[lane]);

    float p1 = (float)(h0 * wf1 * wf2);
    float p2 = (float)(h0 * wf0 * wf2);
    float p3 = (float)(h0 * wf0 * wf1);

    epif[wave][lane] = gv;
    float dv = 0.f;
    for (int m = 0; m < 64; ++m) dv = fmaf(epif[wave][m], Wt1T[m*64 + lane], dv);

    float* co = CU + atom * 192;
    epif[wave][lane] = dv * p1;
    float c0 = 0.f;
    for (int m = 0; m < 64; ++m) c0 = fmaf(epif[wave][m], W2aT[m*64 + lane], c0);
    co[lane] = c0;

    epif[wave][lane] = dv * p2;
    float c1 = 0.f;
    for (int m = 0; m < 64; ++m) c1 = fmaf(epif[wave][m], W2bT[m*64 + lane], c1);
    co[64 + lane] = c1;

    epif[wave][lane] = dv * p3;
    float c2 = 0.f;
    for (int m = 0; m < 64; ++m) c2 = fmaf(epif[wave][m], W2cT[m*64 + lane], c2);
    co[128 + lane] = c2;
}

// ------- backward via derivative coefficient table, d-row in LDS -------
__global__ __launch_bounds__(256) void k_bwd(
    const float* __restrict__ dws, const float4* __restrict__ B4,
    const float* __restrict__ C, float* __restrict__ T)
{
    __shared__ float dsh[4][128];
    int tid = threadIdx.x;
    int wave = tid >> 6, lane = tid & 63;
    int atom = blockIdx.x * 4 + wave;
    int b = atom >> 7, i = atom & 127;
    const float* drow = dws + (atom << 7);
    dsh[wave][lane]      = drow[lane];
    dsh[wave][64 + lane] = drow[64 + lane];
    const float* ci = C + atom * 192;
    float ci0 = ci[lane], ci1 = ci[64 + lane], ci2 = ci[128 + lane];
    float* Tb = T + ((size_t)b << 14);
    const float invh = (float)NI / 10.0f;
    const float4* Bfp = B4 + lane;
    float vm = 0.f;

    #pragma unroll 1
    for (int g = 0; g < 16; ++g) {
        int offb = 1 + (g << 2);
        float tt[4], cA[4], cB[4], cC[4];
        float4 u0[4], u1[4], u2[4];
        #pragma unroll
        for (int p = 0; p < 4; ++p) {
            int aa = (i + offb + p) & 127;
            float d = dsh[wave][aa];
            float fd = fminf(d * invh, (float)NI - 0.001f);
            float jf = floorf(fd);
            tt[p] = fd - jf;
            int j4 = (int)jf * 192;
            u0[p] = Bfp[j4];
            u1[p] = Bfp[j4 + 64];
            u2[p] = Bfp[j4 + 128];
            const float* ca = C + (((b << 7) + aa) * 192);
            cA[p] = ca[lane]; cB[p] = ca[64 + lane]; cC[p] = ca[128 + lane];
        }
        #pragma unroll
        for (int p = 0; p < 4; ++p) {
            float t1 = tt[p];
            float g0 = fmaf(t1, fmaf(t1, fmaf(t1, u0[p].w, u0[p].z), u0[p].y), u0[p].x);
            float g1 = fmaf(t1, fmaf(t1, fmaf(t1, u1[p].w, u1[p].z), u1[p].y), u1[p].x);
            float g2 = fmaf(t1, fmaf(t1, fmaf(t1, u2[p].w, u2[p].z), u2[p].y), u2[p].x);
            float red = (ci0 + cA[p]) * g0 + (ci1 + cB[p]) * g1 + (ci2 + cC[p]) * g2;
            #pragma unroll
            for (int o = 1; o < 64; o <<= 1) red += __shfl_xor(red, o);
            if (lane == (g << 2) + p) vm = red;
        }
    }
    int off = lane + 1;
    if (off < 64 || i < 64) {
        int a = (i + off) & 127;
        Tb[(i << 7) + a] = vm;
        Tb[(a << 7) + i] = vm;
    }
}

__global__ __launch_bounds__(256) void k_force(
    const float* __restrict__ xs, const float* __restrict__ dws,
    const float* __restrict__ T, float* __restrict__ Fr)
{
    int tid = threadIdx.x;
    int wave = tid >> 6, lane = tid & 63;
    int atom = blockIdx.x * 4 + wave;
    int i = atom & 127;
    int b = atom >> 7;
    const float* xb = xs + b * (NN * 3);
    float xi0 = xb[i*3], xi1 = xb[i*3+1], xi2 = xb[i*3+2];
    const float* drow = dws + (atom << 7);
    const float* trow = T + (atom << 7);
    float fx = 0.f, fy = 0.f, fz = 0.f;
    for (int it = lane; it < 127; it += 64) {
        int aa = (i + 1 + it) & 127;
        float coef = trow[aa] / drow[aa];
        fx += coef * (xi0 - xb[aa*3]);
        fy += coef * (xi1 - xb[aa*3+1]);
        fz += coef * (xi2 - xb[aa*3+2]);
    }
    #pragma unroll
    for (int off = 1; off < 64; off <<= 1) {
        fx += __shfl_xor(fx, off);
        fy += __shfl_xor(fy, off);
        fz += __shfl_xor(fz, off);
    }
    if (lane == 0) {
        Fr[atom*3]   = fx;
        Fr[atom*3+1] = fy;
        Fr[atom*3+2] = fz;
    }
}

__global__ __launch_bounds__(128) void k_out(const float* __restrict__ Fr, float* __restrict__ out)
{
    __shared__ float rs[3][128];
    int b = blockIdx.x, n = threadIdx.x;
    float g0 = Fr[(b*128+n)*3], g1 = Fr[(b*128+n)*3+1], g2 = Fr[(b*128+n)*3+2];
    rs[0][n] = g0; rs[1][n] = g1; rs[2][n] = g2;
    __syncthreads();
    for (int s = 64; s > 0; s >>= 1) {
        if (n < s) {
            rs[0][n] += rs[0][n+s];
            rs[1][n] += rs[1][n+s];
            rs[2][n] += rs[2][n+s];
        }
        __syncthreads();
    }
    float m0 = rs[0][0] * (1.f/128.f);
    float m1 = rs[1][0] * (1.f/128.f);
    float m2 = rs[2][0] * (1.f/128.f);
    out[b*384 + n*3 + 0] = m0 - g0;
    out[b*384 + n*3 + 1] = m1 - g1;
    out[b*384 + n*3 + 2] = m2 - g2;
}

extern "C" void kernel_launch(void* const* d_in, const int* in_sizes, int n_in,
                              void* d_out, int out_size, void* d_ws, size_t ws_size,
                              hipStream_t stream)
{
    const float* xs   = (const float*)d_in[1];
    const float* mus  = (const float*)d_in[2];
    const float* gam  = (const float*)d_in[3];
    const float* Wenc = (const float*)d_in[4];
    const float* benc = (const float*)d_in[5];
    const float* W1a  = (const float*)d_in[6];
    const float* b1a  = (const float*)d_in[7];
    const float* W2a  = (const float*)d_in[8];
    const float* b2a  = (const float*)d_in[9];
    const float* W1b  = (const float*)d_in[10];
    const float* b1b  = (const float*)d_in[11];
    const float* W2b  = (const float*)d_in[12];
    const float* b2b  = (const float*)d_in[13];
    const float* W1c  = (const float*)d_in[14];
    const float* b1c  = (const float*)d_in[15];
    const float* W2c  = (const float*)d_in[16];
    const float* b2c  = (const float*)d_in[17];
    const float* Wt1  = (const float*)d_in[18];
    const float* bt1  = (const float*)d_in[19];
    const float* Wt2  = (const float*)d_in[20];

    float* ws  = (float*)d_ws;
    float* dws = ws;
    float* T   = ws + 524288;
    float4* A4 = (float4*)(ws + 1048576);
    float4* B4 = (float4*)(ws + 1540096);
    float* WT  = ws + 2031616;
    float* C   = ws + 2097152;
    float* Fr  = ws + 2883584;
    float* out = (float*)d_out;

    k_dt   <<<2592, 256, 0, stream>>>(xs, dws, W1a, W1b, W1c, b1a, b1b, b1c,
                                      mus, gam, A4, B4, Wt1, W2a, W2b, W2c, WT);
    k_fwdp <<<1024, 256, 0, stream>>>(dws, A4, C);
    k_epi  <<<1024, 256, 0, stream>>>(C, W2a, W2b, W2c, b2a, b2b, b2c,
                                      Wenc, benc, Wt1, bt1, Wt2, WT);
    k_bwd  <<<1024, 256, 0, stream>>>(dws, B4, C, T);
    k_force<<<1024, 256, 0, stream>>>(xs, dws, T, Fr);
    k_out  <<<32, 128, 0, stream>>>(Fr, out);
}